// Round 3
// baseline (212.690 us; speedup 1.0000x reference)
//
#include <hip/hip_runtime.h>
#include <hip/hip_bf16.h>
#include <math.h>

// Problem constants (from reference)
#define MSEG  4096     // number of graphs / segments
#define NNODE 262144   // total nodes
#define DDIM  128      // d_h == d_x == 128
#define CHUNK 64       // nodes per register chunk (avg segment size is 64)
#define PROJ_ROWS 16   // h-rows per block in the proj GEMM

// Kernel 1: segment start offsets (segment_ids is sorted).
// starts[g] = first index i with seg[i] >= g; starts[MSEG] = NNODE.
__global__ __launch_bounds__(256) void seg_starts_kernel(
    const int* __restrict__ seg, int* __restrict__ starts)
{
    int i = blockIdx.x * blockDim.x + threadIdx.x;
    if (i >= NNODE) return;
    int s = seg[i];
    int prev = (i == 0) ? -1 : seg[i - 1];
    for (int g = prev + 1; g <= s; ++g) starts[g] = i;
    if (i == NNODE - 1)
        for (int g = s + 1; g <= MSEG; ++g) starts[g] = NNODE;
}

// Kernel 2: proj = h @ a  (4096x128 @ 128x128 -> 4096x128), into d_ws.
// 256 blocks x 16 rows. `a` staged once per block in LDS (64 KB) ->
// a-traffic is 256x32KB = 16 MB L2 instead of 134 MB when done per segment.
// Wave-uniform r => h_lds reads broadcast; a_lds float2 reads are
// 2-way-per-bank (free on gfx950).
__global__ __launch_bounds__(256) void proj_kernel(
    const float* __restrict__ h, const float* __restrict__ a,
    float* __restrict__ proj)
{
    __shared__ __align__(16) float a_lds[DDIM * DDIM];        // 64 KB
    __shared__ __align__(16) float h_lds[PROJ_ROWS * DDIM];   // 8 KB
    const int tid = threadIdx.x;
    const int g0  = blockIdx.x * PROJ_ROWS;

    const float4* a4  = (const float4*)a;
    float4*       al4 = (float4*)a_lds;
    #pragma unroll
    for (int j = 0; j < (DDIM * DDIM / 4) / 256; ++j)         // 16 iters
        al4[j * 256 + tid] = a4[j * 256 + tid];
    const float4* h4  = (const float4*)(h + (size_t)g0 * DDIM);
    float4*       hl4 = (float4*)h_lds;
    #pragma unroll
    for (int j = 0; j < (PROJ_ROWS * DDIM / 4) / 256; ++j)    // 2 iters
        hl4[j * 256 + tid] = h4[j * 256 + tid];
    __syncthreads();

    const int dp = tid & 63;          // dim pair: dims {2dp, 2dp+1}
    const int rh = tid >> 6;          // wave id -> row group (wave-uniform r)
    const float2* al2 = (const float2*)a_lds;
    #pragma unroll
    for (int rr = 0; rr < PROJ_ROWS / 4; ++rr) {
        const int r = rh * (PROJ_ROWS / 4) + rr;
        float2 p = make_float2(0.f, 0.f);
        #pragma unroll 8
        for (int k = 0; k < DDIM; ++k) {
            const float  hv = h_lds[r * DDIM + k];            // broadcast
            const float2 av = al2[k * 64 + dp];               // stride-1 pairs
            p.x += hv * av.x;
            p.y += hv * av.y;
        }
        ((float2*)(proj + (size_t)(g0 + r) * DDIM))[dp] = p;
    }
}

// Kernel 3: one block per segment, 256 threads.
// Thread (c = tid>>5, q = tid&31) owns rows i = c+8j (j<8) at dims [4q,4q+4).
// x rows live in registers (xv[8]); proj[g] is one L2-hot float4 load.
// Online softmax state (m,l) block-uniform; stats via per-wave butterflies;
// 2 __syncthreads() per chunk.
__global__ __launch_bounds__(256) void attn_seg_kernel(
    const float* __restrict__ x,
    const float* __restrict__ proj,
    const int*   __restrict__ starts,
    float*       __restrict__ out)
{
    __shared__ float s_lds[CHUNK];                    // raw scores of the chunk
    __shared__ __align__(16) float4 racc[256];        // final reduction (4 KB)

    const int g    = blockIdx.x;
    const int tid  = threadIdx.x;
    const int q    = tid & 31;
    const int c    = tid >> 5;
    const int lane = tid & 63;

    const int start = starts[g];
    const int end   = starts[g + 1];

    if (start >= end) {                               // empty segment -> zeros
        if (tid < 32)
            ((float4*)out)[(size_t)g * 32 + tid] = make_float4(0.f, 0.f, 0.f, 0.f);
        return;
    }

    const float4* __restrict__ x4p = (const float4*)x;
    const float4 pj = ((const float4*)(proj + (size_t)g * DDIM))[q];

    // ---- prefetch chunk 0 into registers ---------------------------------
    int n_c = min(CHUNK, end - start);
    float4 xv[8];
    #pragma unroll
    for (int j = 0; j < 8; ++j) {
        const int i = j * 8 + c;
        xv[j] = make_float4(0.f, 0.f, 0.f, 0.f);
        if (i < n_c) xv[j] = x4p[(size_t)(start + i) * (DDIM / 4) + q];
    }

    float m = -INFINITY;                              // running max (uniform)
    float l = 0.f;                                    // running denom (uniform)
    float4 acc = make_float4(0.f, 0.f, 0.f, 0.f);     // out[g][4q..4q+3], rows ≡ c (8)

    int cs = start;
    while (true) {
        // ---- scores from registers: s_i = x_i . proj ---------------------
        #pragma unroll
        for (int j = 0; j < 8; ++j) {
            const int i = j * 8 + c;
            float ps = xv[j].x * pj.x + xv[j].y * pj.y
                     + xv[j].z * pj.z + xv[j].w * pj.w;
            #pragma unroll
            for (int off = 16; off > 0; off >>= 1)    // 32-lane group reduce
                ps += __shfl_down(ps, off, 32);
            if (q == 0 && i < n_c) s_lds[i] = ps;
        }
        __syncthreads();

        // ---- softmax stats, redundantly per wave -------------------------
        float v = (lane < n_c) ? s_lds[lane] : -INFINITY;
        #pragma unroll
        for (int off = 32; off > 0; off >>= 1)
            v = fmaxf(v, __shfl_xor(v, off));
        const float m_new = fmaxf(m, v);
        float e = (lane < n_c) ? __expf(s_lds[lane] - m_new) : 0.f;
        #pragma unroll
        for (int off = 32; off > 0; off >>= 1)
            e += __shfl_xor(e, off);

        const float alpha = __expf(m - m_new);        // exp(-inf)=0 first chunk
        l = l * alpha + e;
        m = m_new;
        acc.x *= alpha; acc.y *= alpha; acc.z *= alpha; acc.w *= alpha;

        // ---- weighted accumulation from registers ------------------------
        #pragma unroll
        for (int j = 0; j < 8; ++j) {
            const int i = j * 8 + c;
            if (i < n_c) {
                const float ei = __expf(s_lds[i] - m_new);   // broadcast read
                acc.x += ei * xv[j].x;
                acc.y += ei * xv[j].y;
                acc.z += ei * xv[j].z;
                acc.w += ei * xv[j].w;
            }
        }

        cs += CHUNK;
        if (cs >= end) break;
        __syncthreads();                              // protect s_lds
        n_c = min(CHUNK, end - cs);
        #pragma unroll
        for (int j = 0; j < 8; ++j) {
            const int i = j * 8 + c;
            xv[j] = make_float4(0.f, 0.f, 0.f, 0.f);
            if (i < n_c) xv[j] = x4p[(size_t)(cs + i) * (DDIM / 4) + q];
        }
    }

    // ---- reduce acc over the 8 row-groups, normalize, store --------------
    racc[tid] = acc;
    __syncthreads();
    if (tid < 32) {
        float4 s = racc[tid];
        #pragma unroll
        for (int cc = 1; cc < 8; ++cc) {
            float4 t = racc[cc * 32 + tid];
            s.x += t.x; s.y += t.y; s.z += t.z; s.w += t.w;
        }
        const float inv = 1.f / l;
        ((float4*)out)[(size_t)g * 32 + tid] =
            make_float4(s.x * inv, s.y * inv, s.z * inv, s.w * inv);
    }
}

extern "C" void kernel_launch(void* const* d_in, const int* in_sizes, int n_in,
                              void* d_out, int out_size, void* d_ws, size_t ws_size,
                              hipStream_t stream) {
    const float* h   = (const float*)d_in[0];   // (M, DH)
    const float* x   = (const float*)d_in[1];   // (N, DX)
    const float* a   = (const float*)d_in[2];   // (DH, DX)
    const int*   seg = (const int*)  d_in[3];   // (N,) sorted
    float* out = (float*)d_out;                 // (M, DX)

    int*   starts = (int*)d_ws;                             // (MSEG+1,)
    float* proj   = (float*)((char*)d_ws + 32768);          // (MSEG, DDIM)

    seg_starts_kernel<<<(NNODE + 255) / 256, 256, 0, stream>>>(seg, starts);
    proj_kernel<<<MSEG / PROJ_ROWS, 256, 0, stream>>>(h, a, proj);
    attn_seg_kernel<<<MSEG, 256, 0, stream>>>(x, proj, starts, out);
}

// Round 4
// 209.668 us; speedup vs baseline: 1.0144x; 1.0144x over previous
//
#include <hip/hip_runtime.h>
#include <hip/hip_bf16.h>
#include <math.h>

// Problem constants (from reference)
#define MSEG  4096     // number of graphs / segments
#define NNODE 262144   // total nodes
#define DDIM  128      // d_h == d_x == 128
#define CHUNK 64       // nodes per register chunk (avg segment size is 64)
#define PROJ_ROWS 16   // h-rows per block in the proj GEMM

// ---------------- DPP cross-lane helpers (VALU pipe, not LDS pipe) --------
// row_shr:N = lane i receives lane i-N within its 16-lane row.
// bound_ctrl=true -> out-of-row source reads 0 (asm "bound_ctrl:0").
template<int CTRL>
__device__ __forceinline__ float dpp_zero(float v) {
    return __int_as_float(__builtin_amdgcn_update_dpp(
        0, __float_as_int(v), CTRL, 0xF, 0xF, true));
}
// invalid source lanes keep their own value (old = src) -> identity for max
template<int CTRL>
__device__ __forceinline__ float dpp_self(float v) {
    int iv = __float_as_int(v);
    return __int_as_float(__builtin_amdgcn_update_dpp(iv, iv, CTRL, 0xF, 0xF, false));
}
__device__ __forceinline__ float rdlane(float v, int lane_const) {
    return __int_as_float(__builtin_amdgcn_readlane(__float_as_int(v), lane_const));
}
// after this, lane 15 of each 16-lane row holds the row sum
__device__ __forceinline__ float row16_sum(float v) {
    v += dpp_zero<0x111>(v);   // row_shr:1
    v += dpp_zero<0x112>(v);   // row_shr:2
    v += dpp_zero<0x114>(v);   // row_shr:4
    v += dpp_zero<0x118>(v);   // row_shr:8
    return v;
}
// block-uniform 64-lane sum/max (result identical in every lane, via SGPRs)
__device__ __forceinline__ float wave_sum64(float v) {
    v = row16_sum(v);
    return (rdlane(v, 15) + rdlane(v, 31)) + (rdlane(v, 47) + rdlane(v, 63));
}
__device__ __forceinline__ float wave_max64(float v) {
    v = fmaxf(v, dpp_self<0x111>(v));
    v = fmaxf(v, dpp_self<0x112>(v));
    v = fmaxf(v, dpp_self<0x114>(v));
    v = fmaxf(v, dpp_self<0x118>(v));
    return fmaxf(fmaxf(rdlane(v, 15), rdlane(v, 31)),
                 fmaxf(rdlane(v, 47), rdlane(v, 63)));
}

// Kernel 1: segment start offsets (segment_ids is sorted).
__global__ __launch_bounds__(256) void seg_starts_kernel(
    const int* __restrict__ seg, int* __restrict__ starts)
{
    int i = blockIdx.x * blockDim.x + threadIdx.x;
    if (i >= NNODE) return;
    int s = seg[i];
    int prev = (i == 0) ? -1 : seg[i - 1];
    for (int g = prev + 1; g <= s; ++g) starts[g] = i;
    if (i == NNODE - 1)
        for (int g = s + 1; g <= MSEG; ++g) starts[g] = NNODE;
}

// Kernel 2: proj = h @ a (4096x128 @ 128x128), a staged once per block in LDS.
__global__ __launch_bounds__(256) void proj_kernel(
    const float* __restrict__ h, const float* __restrict__ a,
    float* __restrict__ proj)
{
    __shared__ __align__(16) float a_lds[DDIM * DDIM];        // 64 KB
    __shared__ __align__(16) float h_lds[PROJ_ROWS * DDIM];   // 8 KB
    const int tid = threadIdx.x;
    const int g0  = blockIdx.x * PROJ_ROWS;

    const float4* a4  = (const float4*)a;
    float4*       al4 = (float4*)a_lds;
    #pragma unroll
    for (int j = 0; j < (DDIM * DDIM / 4) / 256; ++j)
        al4[j * 256 + tid] = a4[j * 256 + tid];
    const float4* h4  = (const float4*)(h + (size_t)g0 * DDIM);
    float4*       hl4 = (float4*)h_lds;
    #pragma unroll
    for (int j = 0; j < (PROJ_ROWS * DDIM / 4) / 256; ++j)
        hl4[j * 256 + tid] = h4[j * 256 + tid];
    __syncthreads();

    const int dp = tid & 63;
    const int rh = tid >> 6;
    const float2* al2 = (const float2*)a_lds;
    #pragma unroll
    for (int rr = 0; rr < PROJ_ROWS / 4; ++rr) {
        const int r = rh * (PROJ_ROWS / 4) + rr;
        float2 p = make_float2(0.f, 0.f);
        #pragma unroll 8
        for (int k = 0; k < DDIM; ++k) {
            const float  hv = h_lds[r * DDIM + k];
            const float2 av = al2[k * 64 + dp];
            p.x += hv * av.x;
            p.y += hv * av.y;
        }
        ((float2*)(proj + (size_t)(g0 + r) * DDIM))[dp] = p;
    }
}

// Kernel 3: one block per segment, 256 threads.
// Mapping: l = tid&15 owns dims [8l, 8l+8) (two float4); r = tid>>4 selects the
// node row i = pass*16 + r. The 16-lane dim-group IS a DPP row, so the score
// reduction is 4 VALU DPP-adds (no LDS pipe). Softmax stats: lane-per-node +
// DPP + readlane -> block-uniform (m,l) in registers; exp computed ONCE per
// node and broadcast via e_lds. 2 barriers per chunk.
__global__ __launch_bounds__(256) void attn_seg_kernel(
    const float* __restrict__ x,
    const float* __restrict__ proj,
    const int*   __restrict__ starts,
    float*       __restrict__ out)
{
    __shared__ float s_lds[CHUNK];                 // raw scores of the chunk
    __shared__ float e_lds[CHUNK];                 // exp(s - m_new)
    __shared__ __align__(16) float4 racc4[512];    // final reduction (8 KB)

    const int g   = blockIdx.x;
    const int tid = threadIdx.x;
    const int l   = tid & 15;                      // dim-octet owner
    const int r   = tid >> 4;                      // row-within-pass (0..15)
    const int L   = tid & 63;                      // lane in wave

    const int start = starts[g];
    const int end   = starts[g + 1];

    if (start >= end) {                            // empty segment -> zeros
        if (tid < 32)
            ((float4*)out)[(size_t)g * 32 + tid] = make_float4(0.f, 0.f, 0.f, 0.f);
        return;
    }

    const float4* __restrict__ x4p = (const float4*)x;
    const float4 pj0 = ((const float4*)proj)[(size_t)g * 32 + 2 * l];
    const float4 pj1 = ((const float4*)proj)[(size_t)g * 32 + 2 * l + 1];

    float m_run = -INFINITY;                       // uniform across threads
    float l_run = 0.f;                             // uniform across threads
    float4 acc0 = make_float4(0.f, 0.f, 0.f, 0.f); // dims 8l..8l+3, rows ≡ r (16)
    float4 acc1 = make_float4(0.f, 0.f, 0.f, 0.f); // dims 8l+4..8l+7

    int cs = start;
    int n_c = min(CHUNK, end - start);
    float4 xv0[4], xv1[4];
    #pragma unroll
    for (int p = 0; p < 4; ++p) {                  // prefetch chunk 0
        const int i = p * 16 + r;
        xv0[p] = make_float4(0.f, 0.f, 0.f, 0.f);
        xv1[p] = make_float4(0.f, 0.f, 0.f, 0.f);
        if (i < n_c) {
            const size_t base = (size_t)(cs + i) * 32 + 2 * l;
            xv0[p] = x4p[base];
            xv1[p] = x4p[base + 1];
        }
    }

    while (true) {
        // ---- scores: 8-dim partial, 16-lane DPP reduce, lane15 writes ----
        #pragma unroll
        for (int p = 0; p < 4; ++p) {
            const int i = p * 16 + r;
            float ps = xv0[p].x * pj0.x + xv0[p].y * pj0.y
                     + xv0[p].z * pj0.z + xv0[p].w * pj0.w
                     + xv1[p].x * pj1.x + xv1[p].y * pj1.y
                     + xv1[p].z * pj1.z + xv1[p].w * pj1.w;
            ps = row16_sum(ps);                    // VALU pipe
            if (l == 15 && i < n_c) s_lds[i] = ps;
        }
        __syncthreads();

        // ---- softmax stats: lane-per-node, all-VALU, block-uniform -------
        const float sv = (L < n_c) ? s_lds[L] : -INFINITY;
        const float m_new = fmaxf(m_run, wave_max64(sv));
        const float ev = (L < n_c) ? __expf(sv - m_new) : 0.f;
        const float lc = wave_sum64(ev);
        if (tid < 64) e_lds[tid] = ev;             // single writer wave-equiv
        const float alpha = __expf(m_run - m_new); // exp(-inf)=0 first chunk
        l_run = l_run * alpha + lc;
        m_run = m_new;
        acc0.x *= alpha; acc0.y *= alpha; acc0.z *= alpha; acc0.w *= alpha;
        acc1.x *= alpha; acc1.y *= alpha; acc1.z *= alpha; acc1.w *= alpha;
        __syncthreads();

        // ---- weighted accumulation (e broadcast from LDS, no exp) --------
        #pragma unroll
        for (int p = 0; p < 4; ++p) {
            const float e = e_lds[p * 16 + r];     // same-addr broadcast
            acc0.x += e * xv0[p].x; acc0.y += e * xv0[p].y;
            acc0.z += e * xv0[p].z; acc0.w += e * xv0[p].w;
            acc1.x += e * xv1[p].x; acc1.y += e * xv1[p].y;
            acc1.z += e * xv1[p].z; acc1.w += e * xv1[p].w;
        }

        cs += CHUNK;
        if (cs >= end) break;
        n_c = min(CHUNK, end - cs);
        #pragma unroll
        for (int p = 0; p < 4; ++p) {
            const int i = p * 16 + r;
            xv0[p] = make_float4(0.f, 0.f, 0.f, 0.f);
            xv1[p] = make_float4(0.f, 0.f, 0.f, 0.f);
            if (i < n_c) {
                const size_t base = (size_t)(cs + i) * 32 + 2 * l;
                xv0[p] = x4p[base];
                xv1[p] = x4p[base + 1];
            }
        }
        __syncthreads();                           // protect s_lds/e_lds
    }

    // ---- final: reduce over the 16 r-threads per dim, normalize, store ---
    racc4[r * 32 + 2 * l]     = acc0;
    racc4[r * 32 + 2 * l + 1] = acc1;
    __syncthreads();
    if (tid < 32) {
        float4 s = racc4[tid];
        #pragma unroll
        for (int rr = 1; rr < 16; ++rr) {
            const float4 t = racc4[rr * 32 + tid];
            s.x += t.x; s.y += t.y; s.z += t.z; s.w += t.w;
        }
        const float inv = 1.f / l_run;
        ((float4*)out)[(size_t)g * 32 + tid] =
            make_float4(s.x * inv, s.y * inv, s.z * inv, s.w * inv);
    }
}

extern "C" void kernel_launch(void* const* d_in, const int* in_sizes, int n_in,
                              void* d_out, int out_size, void* d_ws, size_t ws_size,
                              hipStream_t stream) {
    const float* h   = (const float*)d_in[0];   // (M, DH)
    const float* x   = (const float*)d_in[1];   // (N, DX)
    const float* a   = (const float*)d_in[2];   // (DH, DX)
    const int*   seg = (const int*)  d_in[3];   // (N,) sorted
    float* out = (float*)d_out;                 // (M, DX)

    int*   starts = (int*)d_ws;                             // (MSEG+1,)
    float* proj   = (float*)((char*)d_ws + 32768);          // (MSEG, DDIM)

    seg_starts_kernel<<<(NNODE + 255) / 256, 256, 0, stream>>>(seg, starts);
    proj_kernel<<<MSEG / PROJ_ROWS, 256, 0, stream>>>(h, a, proj);
    attn_seg_kernel<<<MSEG, 256, 0, stream>>>(x, proj, starts, out);
}